// Round 2
// baseline (47.436 us; speedup 1.0000x reference)
//
#include <hip/hip_runtime.h>
#include <math.h>

#define B_TOTAL 2048
#define I_DIM   128
#define O_DIM   128
#define GK      68      // G + k rows in w
#define NKNOT   71      // G + 2k - 1
#define ROWSZ   (I_DIM * O_DIM)   // stride between g-rows in w: 16384 floats

// One block per b: 256 threads = 4 waves.
// Phase 1: threads 0..127 compute basis coeffs for i=tid into LDS.
// Phase 2: wave k accumulates i in [32k, 32k+32), lane covers o0=2*lane
//          (float2 loads -> one 512B coalesced row per wave per load).
// Phase 3: LDS partial reduction across the 4 waves, coalesced store.
__global__ __launch_bounds__(256)
void flashkan_fwd(const float* __restrict__ x,
                  const float* __restrict__ w,
                  const float* __restrict__ t,
                  float* __restrict__ out) {
    __shared__ float sh[I_DIM][6];      // c0..c4, g0 bits (3KB)
    __shared__ float psum[4][O_DIM];    // per-wave partials (2KB)
    __shared__ float t_sh[NKNOT];

    const int tid = threadIdx.x;
    if (tid < NKNOT) t_sh[tid] = t[tid];
    __syncthreads();

    const int b = blockIdx.x;

    // ---- Phase 1: basis per i ----
    if (tid < I_DIM) {
        const int ii = tid;
        const float xv = x[(size_t)b * I_DIM + ii];

        // interval index (searchsorted 'right' - 1, clipped to [3,66])
        int ik = 3 + (int)floorf((xv + 1.0f) * 32.0f);
        ik = min(max(ik, 3), 66);
        while (ik < 66 && xv >= t_sh[ik + 1]) ++ik;
        while (ik > 3 && xv < t_sh[ik]) --ik;

        // de Boor triangular recursion, k=4 (p=3), exact ref order
        float l0, l1, l2, r0, r1, r2;
        float N0 = 1.0f, N1, N2, N3;
        l0 = xv - t_sh[ik];
        r0 = t_sh[ik + 1] - xv;
        {
            float temp = N0 / (r0 + l0);
            N0 = r0 * temp;
            N1 = l0 * temp;
        }
        l1 = xv - t_sh[ik - 1];
        r1 = t_sh[ik + 2] - xv;
        {
            float saved = 0.0f, temp;
            temp = N0 / (r0 + l1);
            N0 = saved + r0 * temp;
            saved = l1 * temp;
            temp = N1 / (r1 + l0);
            N1 = saved + r1 * temp;
            N2 = l0 * temp;
        }
        l2 = xv - t_sh[ik - 2];
        r2 = t_sh[ik + 3] - xv;
        {
            float saved = 0.0f, temp;
            temp = N0 / (r0 + l2);
            N0 = saved + r0 * temp;
            saved = l2 * temp;
            temp = N1 / (r1 + l1);
            N1 = saved + r1 * temp;
            saved = l1 * temp;
            temp = N2 / (r2 + l0);
            N2 = saved + r2 * temp;
            N3 = l0 * temp;
        }
        const float silu = xv / (1.0f + expf(-xv));

        sh[ii][0] = N0;
        sh[ii][1] = N1;
        sh[ii][2] = N2;
        sh[ii][3] = N3;
        sh[ii][4] = silu;
        sh[ii][5] = __int_as_float(ik - 3);   // g0 in [0,63]
    }
    __syncthreads();

    // ---- Phase 2: gather-accumulate, wave-split over i ----
    const int wave = tid >> 6;
    const int lane = tid & 63;
    const int o0   = lane * 2;
    const int i_lo = wave * 32;

    float accx = 0.0f, accy = 0.0f;
    #pragma unroll 4
    for (int ii = i_lo; ii < i_lo + 32; ++ii) {
        const float c0 = sh[ii][0];
        const float c1 = sh[ii][1];
        const float c2 = sh[ii][2];
        const float c3 = sh[ii][3];
        const float c4 = sh[ii][4];
        const int   g0 = __float_as_int(sh[ii][5]);

        const float* base = w + (size_t)ii * O_DIM + o0;
        const float2 v0 = *(const float2*)(base + (size_t)(g0    ) * ROWSZ);
        const float2 v1 = *(const float2*)(base + (size_t)(g0 + 1) * ROWSZ);
        const float2 v2 = *(const float2*)(base + (size_t)(g0 + 2) * ROWSZ);
        const float2 v3 = *(const float2*)(base + (size_t)(g0 + 3) * ROWSZ);
        const float2 v4 = *(const float2*)(base + (size_t)(GK - 1) * ROWSZ);

        accx += c0 * v0.x + c1 * v1.x + c2 * v2.x + c3 * v3.x + c4 * v4.x;
        accy += c0 * v0.y + c1 * v1.y + c2 * v2.y + c3 * v3.y + c4 * v4.y;
    }

    psum[wave][o0]     = accx;
    psum[wave][o0 + 1] = accy;
    __syncthreads();

    // ---- Phase 3: reduce 4 partials, coalesced store ----
    if (tid < O_DIM) {
        const float s = psum[0][tid] + psum[1][tid] + psum[2][tid] + psum[3][tid];
        out[(size_t)b * O_DIM + tid] = s;
    }
}

extern "C" void kernel_launch(void* const* d_in, const int* in_sizes, int n_in,
                              void* d_out, int out_size, void* d_ws, size_t ws_size,
                              hipStream_t stream) {
    const float* x = (const float*)d_in[0];
    const float* w = (const float*)d_in[1];
    const float* t = (const float*)d_in[2];
    float* out = (float*)d_out;

    dim3 grid(B_TOTAL);
    dim3 block(256);
    flashkan_fwd<<<grid, block, 0, stream>>>(x, w, t, out);
}

// Round 3
// 33.449 us; speedup vs baseline: 1.4182x; 1.4182x over previous
//
#include <hip/hip_runtime.h>
#include <math.h>

#define B_TOTAL 2048
#define I_DIM   128
#define O_DIM   128
#define GK      68                  // G + k rows in w
#define NKNOT   71                  // G + 2k - 1
#define BT      64                  // b per block
#define RI      16                  // i per block
#define NR      (I_DIM / RI)        // 8 i-ranges
#define THREADS 512
#define SLICE_FLOATS (GK * O_DIM)   // 8704 floats = 34816 B per i-slice
#define CHUNKS  (SLICE_FLOATS * 4 / 1024)   // 34 chunks of 1KB (64 lanes x 16B)
#define WS_NEED ((size_t)NR * B_TOTAL * O_DIM * 4)   // 8 MB partials

// Main kernel: grid = 32 b-tiles x 8 i-ranges = 256 blocks, 512 threads (8 waves).
// Per i: stage w[:, i, :] (34.8KB) into LDS (double-buffered, global_load_lds),
// each wave accumulates 8 b's: 5 conflict-free ds_read_b64 row reads per (b,i).
template<bool USE_WS>
__global__ __launch_bounds__(THREADS)
void flashkan_main(const float* __restrict__ x,
                   const float* __restrict__ w,
                   const float* __restrict__ t,
                   float* __restrict__ dst) {
    __shared__ float wbuf[2][SLICE_FLOATS];     // 69632 B
    __shared__ float coef[BT * RI * 6];         // 24576 B
    __shared__ float t_sh[NKNOT];

    const int tid  = threadIdx.x;
    const int bid  = blockIdx.x;
    const int bt   = bid >> 3;      // 0..31
    const int r    = bid & 7;       // 0..7
    const int b0   = bt * BT;
    const int i0   = r * RI;
    const int wave = tid >> 6;
    const int lane = tid & 63;

    if (tid < NKNOT) t_sh[tid] = t[tid];
    __syncthreads();

    // ---- coeff phase: 64b x 16i = 1024 pairs, 2 per thread ----
    for (int p = tid; p < BT * RI; p += THREADS) {
        const int bl = p >> 4;
        const int ii = p & (RI - 1);
        const float xv = x[(size_t)(b0 + bl) * I_DIM + (i0 + ii)];

        int ik = 3 + (int)floorf((xv + 1.0f) * 32.0f);
        ik = min(max(ik, 3), 66);
        while (ik < 66 && xv >= t_sh[ik + 1]) ++ik;
        while (ik > 3 && xv < t_sh[ik]) --ik;

        float l0, l1, l2, r0, r1, r2;
        float N0 = 1.0f, N1, N2, N3;
        l0 = xv - t_sh[ik];
        r0 = t_sh[ik + 1] - xv;
        {
            float temp = N0 / (r0 + l0);
            N0 = r0 * temp;
            N1 = l0 * temp;
        }
        l1 = xv - t_sh[ik - 1];
        r1 = t_sh[ik + 2] - xv;
        {
            float saved = 0.0f, temp;
            temp = N0 / (r0 + l1);
            N0 = saved + r0 * temp;
            saved = l1 * temp;
            temp = N1 / (r1 + l0);
            N1 = saved + r1 * temp;
            N2 = l0 * temp;
        }
        l2 = xv - t_sh[ik - 2];
        r2 = t_sh[ik + 3] - xv;
        {
            float saved = 0.0f, temp;
            temp = N0 / (r0 + l2);
            N0 = saved + r0 * temp;
            saved = l2 * temp;
            temp = N1 / (r1 + l1);
            N1 = saved + r1 * temp;
            saved = l1 * temp;
            temp = N2 / (r2 + l0);
            N2 = saved + r2 * temp;
            N3 = l0 * temp;
        }
        const float silu = xv / (1.0f + expf(-xv));

        float* cp = &coef[p * 6];
        cp[0] = N0; cp[1] = N1; cp[2] = N2; cp[3] = N3;
        cp[4] = silu;
        cp[5] = __int_as_float(ik - 3);
    }

    // ---- staging helper: slice w[:, i_abs, :] -> wbuf[sel] ----
    auto stage = [&](int sel, int i_abs) {
        for (int c = wave; c < CHUNKS; c += 8) {          // wave-uniform loop
            const int f = c * 256 + lane * 4;             // float idx in slice
            const int g = f >> 7;                         // row
            const int o = f & (O_DIM - 1);
            const float* src = w + ((size_t)g * I_DIM + i_abs) * O_DIM + o;
            void* dstp = (void*)&wbuf[sel][c * 256];      // wave-uniform base
            __builtin_amdgcn_global_load_lds(
                (const __attribute__((address_space(1))) void*)src,
                (__attribute__((address_space(3))) void*)dstp,
                16, 0, 0);
        }
    };

    stage(0, i0);
    __syncthreads();   // coeffs + slice 0 ready (drains vmcnt before barrier)

    float2 acc[8];
    #pragma unroll
    for (int bl = 0; bl < 8; ++bl) acc[bl] = make_float2(0.0f, 0.0f);

    for (int ii = 0; ii < RI; ++ii) {
        if (ii + 1 < RI) stage((ii + 1) & 1, i0 + ii + 1);   // issue early
        const float* buf = wbuf[ii & 1];

        #pragma unroll
        for (int bl = 0; bl < 8; ++bl) {
            const int blg = wave * 8 + bl;
            const float* cp = &coef[(blg * RI + ii) * 6];    // uniform -> broadcast
            const float c0 = cp[0], c1 = cp[1], c2 = cp[2], c3 = cp[3], c4 = cp[4];
            const int   g0 = __float_as_int(cp[5]);

            const float2 v0 = ((const float2*)(buf + (size_t)(g0    ) * O_DIM))[lane];
            const float2 v1 = ((const float2*)(buf + (size_t)(g0 + 1) * O_DIM))[lane];
            const float2 v2 = ((const float2*)(buf + (size_t)(g0 + 2) * O_DIM))[lane];
            const float2 v3 = ((const float2*)(buf + (size_t)(g0 + 3) * O_DIM))[lane];
            const float2 v4 = ((const float2*)(buf + (size_t)(GK - 1) * O_DIM))[lane];

            acc[bl].x += c0 * v0.x + c1 * v1.x + c2 * v2.x + c3 * v3.x + c4 * v4.x;
            acc[bl].y += c0 * v0.y + c1 * v1.y + c2 * v2.y + c3 * v3.y + c4 * v4.y;
        }
        __syncthreads();   // compiler drains vmcnt+lgkm: next slice landed, reads done
    }

    // ---- epilogue ----
    #pragma unroll
    for (int bl = 0; bl < 8; ++bl) {
        const int b = b0 + wave * 8 + bl;
        if (USE_WS) {
            float2* dp = (float2*)(dst + ((size_t)r * B_TOTAL + b) * O_DIM) + lane;
            *dp = acc[bl];
        } else {
            atomicAdd(&dst[(size_t)b * O_DIM + 2 * lane],     acc[bl].x);
            atomicAdd(&dst[(size_t)b * O_DIM + 2 * lane + 1], acc[bl].y);
        }
    }
}

// Reduce: out[b][o] = sum_r ws[r][b][o]; 65536 float4-threads.
__global__ __launch_bounds__(256)
void flashkan_reduce(const float* __restrict__ ws, float* __restrict__ out) {
    const int f = blockIdx.x * 256 + threadIdx.x;       // < 65536
    const float4* base = (const float4*)ws + f;
    float4 s = make_float4(0.0f, 0.0f, 0.0f, 0.0f);
    #pragma unroll
    for (int r2 = 0; r2 < NR; ++r2) {
        const float4 v = base[(size_t)r2 * (B_TOTAL * O_DIM / 4)];
        s.x += v.x; s.y += v.y; s.z += v.z; s.w += v.w;
    }
    ((float4*)out)[f] = s;
}

extern "C" void kernel_launch(void* const* d_in, const int* in_sizes, int n_in,
                              void* d_out, int out_size, void* d_ws, size_t ws_size,
                              hipStream_t stream) {
    const float* x = (const float*)d_in[0];
    const float* w = (const float*)d_in[1];
    const float* t = (const float*)d_in[2];
    float* out = (float*)d_out;

    dim3 grid(32 * NR);     // 256 blocks
    dim3 block(THREADS);

    if (ws_size >= WS_NEED) {
        float* ws = (float*)d_ws;
        flashkan_main<true><<<grid, block, 0, stream>>>(x, w, t, ws);
        flashkan_reduce<<<B_TOTAL * O_DIM / 4 / 256, 256, 0, stream>>>(ws, out);
    } else {
        hipMemsetAsync(out, 0, (size_t)out_size * sizeof(float), stream);
        flashkan_main<false><<<grid, block, 0, stream>>>(x, w, t, out);
    }
}

// Round 4
// 31.945 us; speedup vs baseline: 1.4849x; 1.0471x over previous
//
#include <hip/hip_runtime.h>
#include <math.h>

#define B_TOTAL 2048
#define I_DIM   128
#define O_DIM   128
#define GK      68                  // G + k rows in w
#define NKNOT   71                  // G + 2k - 1
#define BT      64                  // b per block
#define RI      8                   // i per block
#define NR      (I_DIM / RI)        // 16 i-ranges
#define THREADS 512
#define SLICE_FLOATS (GK * O_DIM)   // 8704 floats = 34816 B per i-slice
#define CHUNKS  (SLICE_FLOATS / 256)        // 34 chunks of 1KB (64 lanes x 16B)
#define WS_NEED ((size_t)NR * B_TOTAL * O_DIM * 4)   // 16 MB partials

__device__ __forceinline__ float rdlanef(float v, int l) {
    return __int_as_float(__builtin_amdgcn_readlane(__float_as_int(v), l));
}

// grid = 32 b-tiles x 16 i-ranges = 512 blocks (2/CU), 512 threads (8 waves).
// Coefs: per-wave in registers (lane l owns pair p=l: bl=l>>3, ii=l&7),
// broadcast in the accumulate loop via v_readlane (no DS traffic).
// Per i: stage w[:, i, :] (34.8KB) into LDS double-buffered (global_load_lds),
// wave accumulates its 8 b's; silu row (g=67) hoisted per-ii.
template<bool USE_WS>
__global__ __launch_bounds__(THREADS, 4)
void flashkan_main(const float* __restrict__ x,
                   const float* __restrict__ w,
                   const float* __restrict__ t,
                   float* __restrict__ dst) {
    __shared__ float wbuf[2][SLICE_FLOATS];     // 69632 B
    __shared__ float t_sh[NKNOT];

    const int tid  = threadIdx.x;
    const int bid  = blockIdx.x;
    const int bt   = bid >> 4;      // 0..31
    const int r    = bid & 15;      // 0..15
    const int b0   = bt * BT;
    const int i0   = r * RI;
    const int wave = tid >> 6;
    const int lane = tid & 63;

    if (tid < NKNOT) t_sh[tid] = t[tid];
    __syncthreads();

    // ---- per-wave coef phase: lane owns (bl = lane>>3, ii = lane&7) ----
    float cf0, cf1, cf2, cf3, cf4;
    int   cg;
    {
        const int bl = lane >> 3;
        const int ii = lane & 7;
        const float xv = x[(size_t)(b0 + wave * 8 + bl) * I_DIM + (i0 + ii)];

        int ik = 3 + (int)floorf((xv + 1.0f) * 32.0f);
        ik = min(max(ik, 3), 66);
        while (ik < 66 && xv >= t_sh[ik + 1]) ++ik;
        while (ik > 3 && xv < t_sh[ik]) --ik;

        float l0, l1, l2, r0, r1, r2;
        float N0 = 1.0f, N1, N2, N3;
        l0 = xv - t_sh[ik];
        r0 = t_sh[ik + 1] - xv;
        {
            float temp = N0 / (r0 + l0);
            N0 = r0 * temp;
            N1 = l0 * temp;
        }
        l1 = xv - t_sh[ik - 1];
        r1 = t_sh[ik + 2] - xv;
        {
            float saved = 0.0f, temp;
            temp = N0 / (r0 + l1);
            N0 = saved + r0 * temp;
            saved = l1 * temp;
            temp = N1 / (r1 + l0);
            N1 = saved + r1 * temp;
            N2 = l0 * temp;
        }
        l2 = xv - t_sh[ik - 2];
        r2 = t_sh[ik + 3] - xv;
        {
            float saved = 0.0f, temp;
            temp = N0 / (r0 + l2);
            N0 = saved + r0 * temp;
            saved = l2 * temp;
            temp = N1 / (r1 + l1);
            N1 = saved + r1 * temp;
            saved = l1 * temp;
            temp = N2 / (r2 + l0);
            N2 = saved + r2 * temp;
            N3 = l0 * temp;
        }
        cf0 = N0; cf1 = N1; cf2 = N2; cf3 = N3;
        cf4 = xv / (1.0f + expf(-xv));
        cg  = ik - 3;
    }

    // ---- staging: slice w[:, i_abs, :] -> wbuf[sel] ----
    auto stage = [&](int sel, int i_abs) {
        for (int c = wave; c < CHUNKS; c += 8) {          // wave-uniform loop
            const int f = c * 256 + lane * 4;
            const int g = f >> 7;
            const int o = f & (O_DIM - 1);
            const float* src = w + ((size_t)g * I_DIM + i_abs) * O_DIM + o;
            void* dstp = (void*)&wbuf[sel][c * 256];      // wave-uniform base
            __builtin_amdgcn_global_load_lds(
                (const __attribute__((address_space(1))) void*)src,
                (__attribute__((address_space(3))) void*)dstp,
                16, 0, 0);
        }
    };

    float2 acc[8];
    #pragma unroll
    for (int bl = 0; bl < 8; ++bl) acc[bl] = make_float2(0.0f, 0.0f);

    auto compute = [&](int ii, const float* buf) {
        const float2 v4 = ((const float2*)(buf + 67 * O_DIM))[lane];  // silu row
        #pragma unroll
        for (int bl = 0; bl < 8; ++bl) {
            const int src = (bl << 3) | ii;               // owning lane (uniform)
            const float c0 = rdlanef(cf0, src);
            const float c1 = rdlanef(cf1, src);
            const float c2 = rdlanef(cf2, src);
            const float c3 = rdlanef(cf3, src);
            const float c4 = rdlanef(cf4, src);
            const int   g0 = __builtin_amdgcn_readlane(cg, src);

            const float2* rp = (const float2*)(buf + (size_t)g0 * O_DIM) + lane;
            const float2 v0 = rp[0];
            const float2 v1 = rp[64];
            const float2 v2 = rp[128];
            const float2 v3 = rp[192];

            acc[bl].x += c0 * v0.x + c1 * v1.x + c2 * v2.x + c3 * v3.x + c4 * v4.x;
            acc[bl].y += c0 * v0.y + c1 * v1.y + c2 * v2.y + c3 * v3.y + c4 * v4.y;
        }
    };

    stage(0, i0);
    __syncthreads();   // slice 0 landed (compiler drains vmcnt at barrier)

    for (int iib = 0; iib < RI; iib += 2) {
        stage(1, i0 + iib + 1);                 // prefetch into buf 1
        compute(iib, wbuf[0]);
        __syncthreads();                        // buf1 landed, buf0 reads done
        if (iib + 2 < RI) stage(0, i0 + iib + 2);
        compute(iib + 1, wbuf[1]);
        __syncthreads();
    }

    // ---- epilogue ----
    #pragma unroll
    for (int bl = 0; bl < 8; ++bl) {
        const int b = b0 + wave * 8 + bl;
        if (USE_WS) {
            float2* dp = (float2*)(dst + ((size_t)r * B_TOTAL + b) * O_DIM) + lane;
            *dp = acc[bl];
        } else {
            atomicAdd(&dst[(size_t)b * O_DIM + 2 * lane],     acc[bl].x);
            atomicAdd(&dst[(size_t)b * O_DIM + 2 * lane + 1], acc[bl].y);
        }
    }
}

// Reduce: out[b][o] = sum_r ws[r][b][o]
__global__ __launch_bounds__(256)
void flashkan_reduce(const float* __restrict__ ws, float* __restrict__ out) {
    const int f = blockIdx.x * 256 + threadIdx.x;       // < 65536
    const float4* base = (const float4*)ws + f;
    float4 s = make_float4(0.0f, 0.0f, 0.0f, 0.0f);
    #pragma unroll
    for (int r2 = 0; r2 < NR; ++r2) {
        const float4 v = base[(size_t)r2 * (B_TOTAL * O_DIM / 4)];
        s.x += v.x; s.y += v.y; s.z += v.z; s.w += v.w;
    }
    ((float4*)out)[f] = s;
}

extern "C" void kernel_launch(void* const* d_in, const int* in_sizes, int n_in,
                              void* d_out, int out_size, void* d_ws, size_t ws_size,
                              hipStream_t stream) {
    const float* x = (const float*)d_in[0];
    const float* w = (const float*)d_in[1];
    const float* t = (const float*)d_in[2];
    float* out = (float*)d_out;

    dim3 grid(32 * NR);     // 512 blocks = 2/CU
    dim3 block(THREADS);

    if (ws_size >= WS_NEED) {
        float* ws = (float*)d_ws;
        flashkan_main<true><<<grid, block, 0, stream>>>(x, w, t, ws);
        flashkan_reduce<<<B_TOTAL * O_DIM / 4 / 256, 256, 0, stream>>>(ws, out);
    } else {
        hipMemsetAsync(out, 0, (size_t)out_size * sizeof(float), stream);
        flashkan_main<false><<<grid, block, 0, stream>>>(x, w, t, out);
    }
}